// Round 12
// baseline (262.089 us; speedup 1.0000x reference)
//
#include <hip/hip_runtime.h>
#include <math.h>

// B=4096, IN=1024, H=2048, OUT=1024
// cosmic layer == broadcast prob[r] = (1/H)*(prod_{d,k} cos(cw[d,r,k]))^2
// Network = 6 fp16-MFMA GEMMs (16x16x32) with fused bias/relu/tanh epilogues.
//
// r12: r9 structure + r11 geometry. G0-G4: 256x128 tile, BK=32, 256 thr
// (4 waves 2x2, per-wave 128x64 -> reads/MFMA=0.375), tri-buffer 72 KB ->
// 2 blocks/CU (2 independent barrier domains, m114), ONE barrier + counted
// vmcnt(6) per K-tile (T4). Conflict-free BK=32 via in-LDS granule perm
// L(row,cc)=row*4+(cc^(row&3)): staging stays linear gld_lds with XOR on
// the GLOBAL source granule (rule 21, same 64B segment -> coalescing
// unchanged); b128 frag reads land uniform 8 lanes/bank-group (zero excess
// conflict). Row-major global layouts everywhere (coalesced epilogue).
// G5 keeps the r9 BK=64 dbuf template. setprio (T5), XCD swizzle (T1).

typedef _Float16 f16;
typedef _Float16 f16x8 __attribute__((ext_vector_type(8)));
typedef _Float16 f16x4 __attribute__((ext_vector_type(4)));
typedef float f32x4 __attribute__((ext_vector_type(4)));

#define GLD16(gp, lp) __builtin_amdgcn_global_load_lds( \
    (const __attribute__((address_space(1))) unsigned int*)(gp), \
    (__attribute__((address_space(3))) unsigned int*)(lp), 16, 0, 0)

__device__ __forceinline__ float tanh_fast(float x) {
  return 1.0f - 2.0f / (__expf(2.0f * x) + 1.0f);
}

// ---------------- fp32 -> fp16 cast (row-major) ----------------
__global__ void cast_f32_f16(const float* __restrict__ in, f16* __restrict__ out, int n4) {
  int i = blockIdx.x * 256 + threadIdx.x;
  if (i < n4) {
    float4 v = ((const float4*)in)[i];
    f16x4 o = { (f16)v.x, (f16)v.y, (f16)v.z, (f16)v.w };
    ((f16x4*)out)[i] = o;
  }
}

// ------- merged cast+transpose: W (K,N) f32 -> WT (N,K) f16 row-major -------
struct TD { const float* src; f16* dst; int K; int N; };
struct TD6 { TD d[6]; };

__global__ void cast_transpose6(TD6 a) {
  TD d = a.d[blockIdx.z];
  const int bx = blockIdx.x * 64;   // N
  const int by = blockIdx.y * 32;   // K
  if (bx >= d.N || by >= d.K) return;
  __shared__ float tile[32][68];
  const int t = threadIdx.x;
#pragma unroll
  for (int pass = 0; pass < 2; ++pass) {
    int idx = t + pass * 256;
    int row = idx >> 4;
    int c4  = (idx & 15) * 4;
    float4 v = *(const float4*)&d.src[(size_t)(by + row) * d.N + bx + c4];
    *(float4*)&tile[row][c4] = v;
  }
  __syncthreads();
  const int nl = t >> 2;
  const int k8 = (t & 3) * 8;
  f16x8 o;
#pragma unroll
  for (int j = 0; j < 8; ++j) o[j] = (f16)tile[k8 + j][nl];
  *(f16x8*)&d.dst[(size_t)(bx + nl) * d.K + by + k8] = o;
}

// ---------------- cosmic prob, 2-pass, both tensors fused ----------------
__global__ void cosmic_pp2(const float* __restrict__ cw1, const float* __restrict__ cw2,
                           float* __restrict__ pp, int H) {
  int i = blockIdx.x * 256 + threadIdx.x;   // 0 .. 16H
  if (i >= 16 * H) return;
  const float* cw = (i < 8 * H) ? cw1 : cw2;
  int j = (i < 8 * H) ? i : i - 8 * H;
  const float* a = cw + (size_t)j * H;
  pp[i] = cosf(a[0]) * cosf(a[1]) * cosf(a[2]);
}
__global__ void cosmic_fin2(const float* __restrict__ pp, float* __restrict__ p1,
                            float* __restrict__ p2, int H) {
  int r = blockIdx.x * 256 + threadIdx.x;   // 0 .. 2H
  if (r >= 2 * H) return;
  int rr = (r < H) ? r : r - H;
  const float* base = pp + ((r < H) ? 0 : 8 * H);
  float p = 1.0f;
#pragma unroll
  for (int d = 0; d < 8; ++d) p *= base[d * H + rr];
  float v = p * p / (float)H;
  if (r < H) p1[rr] = v; else p2[rr] = v;
}

// ======== r12 main GEMM: 256x128, BK=32, 4 waves of 128x64, tri-buffer ========
// A: (M,K) f16 row-major. BT: (N,K) f16 row-major.
// EPI 0: relu->f16  1: tanh(+prob)->f16
template <int EPI>
__global__ __launch_bounds__(256, 2)
void gemm12(const f16* __restrict__ A, const f16* __restrict__ BT,
            const float* __restrict__ bias, const float* __restrict__ prob,
            f16* __restrict__ Ch, int M, int N, int K, int GX) {
  constexpr int BM = 256, BN = 128;
  constexpr int ASZ = BM * 32;          // 8192 f16 per A buffer
  constexpr int BSZ = BN * 32;          // 4096 f16 per B buffer
  __shared__ f16 lds[3 * (ASZ + BSZ)];  // 72 KB tri-buffer -> 2 blocks/CU
  f16* As = lds;
  f16* Bs = lds + 3 * ASZ;

  const int t = threadIdx.x;
  const int nwg = gridDim.x, bid = blockIdx.x;
  const int swz = (bid & 7) * (nwg >> 3) + (bid >> 3);   // XCD (nwg%8==0)
  const int bx = swz % GX, by = swz / GX;
  const int m0 = by * BM, n0 = bx * BN;

  // staging: LDS granule g linear; global source granule = (row, cc) with
  // row=g>>2, cc=(g&3)^(row&3) -- XOR within the row's 64B segment (rule 21).
  auto stage_all = [&](int kt, int buf) {
    const int k0 = kt << 5;
#pragma unroll
    for (int q = 0; q < 4; ++q) {           // A: 1024 granules
      int g = q * 256 + t;
      int row = g >> 2;
      int cc = (g & 3) ^ (row & 3);
      GLD16(A + (size_t)(m0 + row) * K + k0 + cc * 8, As + buf * ASZ + g * 8);
    }
#pragma unroll
    for (int q = 0; q < 2; ++q) {           // B: 512 granules
      int g = q * 256 + t;
      int row = g >> 2;
      int cc = (g & 3) ^ (row & 3);
      GLD16(BT + (size_t)(n0 + row) * K + k0 + cc * 8, Bs + buf * BSZ + g * 8);
    }
  };

  const int wave = t >> 6, lane = t & 63;
  const int wr = wave >> 1, wc = wave & 1;   // 2M x 2N; per-wave 128x64
  const int l16 = lane & 15, kq = lane >> 4;

  f32x4 acc[8][4] = {};
  const int nt = K >> 5;

  stage_all(0, 0);
  stage_all(1, 1);
  int cur = 0;
  for (int kt = 0; kt < nt; ++kt) {
    // tile kt staged (kt+1's 6 stay in flight; never drains except tail)
    if (kt + 1 < nt) asm volatile("s_waitcnt vmcnt(6)" ::: "memory");
    else             asm volatile("s_waitcnt vmcnt(0)" ::: "memory");
    __builtin_amdgcn_s_barrier();
    int sb = cur + 2; if (sb >= 3) sb -= 3;
    if (kt + 2 < nt) stage_all(kt + 2, sb);   // buf sb fully consumed in kt-1

    const f16* Ab = As + cur * ASZ;
    const f16* Bb = Bs + cur * BSZ;
    f16x8 b[4], a[8];
#pragma unroll
    for (int nr = 0; nr < 4; ++nr) {
      int row = wc * 64 + nr * 16 + l16;
      int L = row * 4 + (kq ^ (row & 3));
      b[nr] = *(const f16x8*)&Bb[L * 8];
    }
    __builtin_amdgcn_sched_barrier(0);        // pin: b reads issue first
#pragma unroll
    for (int mr = 0; mr < 8; ++mr) {
      int row = wr * 128 + mr * 16 + l16;
      int L = row * 4 + (kq ^ (row & 3));
      a[mr] = *(const f16x8*)&Ab[L * 8];
    }
    // cluster 0: b[0..3]+a[0..3] done (a[4..7] hide under MFMA; DS in-order)
    asm volatile("s_waitcnt lgkmcnt(4)" ::: "memory");
    __builtin_amdgcn_sched_barrier(0);
    __builtin_amdgcn_s_setprio(1);
#pragma unroll
    for (int mr = 0; mr < 4; ++mr)
#pragma unroll
      for (int nr = 0; nr < 4; ++nr)
        acc[mr][nr] = __builtin_amdgcn_mfma_f32_16x16x32_f16(a[mr], b[nr], acc[mr][nr], 0, 0, 0);
    __builtin_amdgcn_s_setprio(0);
    asm volatile("s_waitcnt lgkmcnt(0)" ::: "memory");
    __builtin_amdgcn_sched_barrier(0);
    __builtin_amdgcn_s_setprio(1);
#pragma unroll
    for (int mr = 4; mr < 8; ++mr)
#pragma unroll
      for (int nr = 0; nr < 4; ++nr)
        acc[mr][nr] = __builtin_amdgcn_mfma_f32_16x16x32_f16(a[mr], b[nr], acc[mr][nr], 0, 0, 0);
    __builtin_amdgcn_s_setprio(0);
    cur = (cur + 1 == 3) ? 0 : cur + 1;
  }

  // epilogue: 16x16 C/D layout col=lane&15, row=(lane>>4)*4+q; row-major out
#pragma unroll
  for (int nr = 0; nr < 4; ++nr) {
    const int col = n0 + wc * 64 + nr * 16 + l16;
    float bn = bias[col];
    if (EPI == 1) bn += prob[col];
#pragma unroll
    for (int mr = 0; mr < 8; ++mr) {
      const int rbase = m0 + wr * 128 + mr * 16 + kq * 4;
#pragma unroll
      for (int q = 0; q < 4; ++q) {
        float v = acc[mr][nr][q] + bn;
        if (EPI == 1) v = tanh_fast(v);
        else v = fmaxf(v, 0.0f);
        Ch[(size_t)(rbase + q) * N + col] = (f16)v;
      }
    }
  }
}

// ======== r9 GEMM template (G5: 128x64, BK=64, dbuf, 2-3 blk/CU) ========
template <int EPI, int BM, int BN, int MINW>
__global__ __launch_bounds__(256, MINW)
void gemm_f16(const f16* __restrict__ A, const f16* __restrict__ BT,
              const float* __restrict__ bias, const float* __restrict__ prob,
              f16* __restrict__ Ch, float* __restrict__ Cf,
              int M, int N, int K, int GX) {
  constexpr int ASZ = BM * 64;
  constexpr int BSZ = BN * 64;
  constexpr int MR  = BM / 32;
  constexpr int NR  = BN / 32;
  constexpr int RA  = ASZ / 2048;
  constexpr int RB  = BSZ / 2048;
  constexpr int NLD = RA + RB;
  __shared__ f16 lds[2 * (ASZ + BSZ)];
  f16* As = lds;
  f16* Bs = lds + 2 * ASZ;

  const int t = threadIdx.x;
  const int nwg = gridDim.x, bid = blockIdx.x;
  const int swz = (bid & 7) * (nwg >> 3) + (bid >> 3);
  const int bx = swz % GX, by = swz / GX;
  const int m0 = by * BM, n0 = bx * BN;

  auto stage_all = [&](int kt, int buf) {
    const int k0 = kt << 6;
#pragma unroll
    for (int q = 0; q < RA; ++q) {
      int F = q * 2048 + t * 8;
      int r = F >> 6, c = (F >> 3) & 7;
      GLD16(A + (size_t)(m0 + r) * K + k0 + ((c ^ (r & 7)) << 3), As + buf * ASZ + F);
    }
#pragma unroll
    for (int q = 0; q < RB; ++q) {
      int F = q * 2048 + t * 8;
      int r = F >> 6, c = (F >> 3) & 7;
      GLD16(BT + (size_t)(n0 + r) * K + k0 + ((c ^ (r & 7)) << 3), Bs + buf * BSZ + F);
    }
  };

  const int wave = t >> 6, lane = t & 63;
  const int wr = wave >> 1, wc = wave & 1;
  const int l16 = lane & 15, kq = lane >> 4;

  f32x4 acc[MR][NR] = {};

  const int nt = K >> 6;
  stage_all(0, 0);
  stage_all(1, 1);
  int cur = 0;
  for (int kt = 0; kt < nt; ++kt) {
    if (kt + 1 < nt) asm volatile("s_waitcnt vmcnt(%0)" :: "i"(NLD) : "memory");
    else             asm volatile("s_waitcnt vmcnt(0)" ::: "memory");
    __builtin_amdgcn_s_barrier();

    const f16* Ab = As + cur * ASZ;
    const f16* Bb = Bs + cur * BSZ;
    f16x8 a[2][MR], b[2][NR];
#pragma unroll
    for (int s = 0; s < 2; ++s) {
      const int cc = s * 4 + kq;
#pragma unroll
      for (int mr = 0; mr < MR; ++mr) {
        int row = wr * (MR * 16) + mr * 16 + l16;
        a[s][mr] = *(const f16x8*)&Ab[row * 64 + ((cc ^ (row & 7)) << 3)];
      }
#pragma unroll
      for (int nr = 0; nr < NR; ++nr) {
        int row = wc * (NR * 16) + nr * 16 + l16;
        b[s][nr] = *(const f16x8*)&Bb[row * 64 + ((cc ^ (row & 7)) << 3)];
      }
      __builtin_amdgcn_sched_barrier(0);
    }
    asm volatile("s_waitcnt lgkmcnt(%0)" :: "i"(MR + NR) : "memory");
    __builtin_amdgcn_sched_barrier(0);
    __builtin_amdgcn_s_setprio(1);
#pragma unroll
    for (int mr = 0; mr < MR; ++mr)
#pragma unroll
      for (int nr = 0; nr < NR; ++nr)
        acc[mr][nr] = __builtin_amdgcn_mfma_f32_16x16x32_f16(a[0][mr], b[0][nr], acc[mr][nr], 0, 0, 0);
    __builtin_amdgcn_s_setprio(0);
    asm volatile("s_waitcnt lgkmcnt(0)" ::: "memory");
    __builtin_amdgcn_sched_barrier(0);
    __builtin_amdgcn_s_barrier();
    if (kt + 2 < nt) stage_all(kt + 2, cur);
    __builtin_amdgcn_s_setprio(1);
#pragma unroll
    for (int mr = 0; mr < MR; ++mr)
#pragma unroll
      for (int nr = 0; nr < NR; ++nr)
        acc[mr][nr] = __builtin_amdgcn_mfma_f32_16x16x32_f16(a[1][mr], b[1][nr], acc[mr][nr], 0, 0, 0);
    __builtin_amdgcn_s_setprio(0);
    cur ^= 1;
  }

#pragma unroll
  for (int nr = 0; nr < NR; ++nr) {
    const int col = n0 + wc * (NR * 16) + nr * 16 + l16;
    float bn = bias[col];
    if (EPI == 1) bn += prob[col];
#pragma unroll
    for (int mr = 0; mr < MR; ++mr) {
      const int rbase = m0 + wr * (MR * 16) + mr * 16 + kq * 4;
#pragma unroll
      for (int q = 0; q < 4; ++q) {
        float v = acc[mr][nr][q] + bn;
        if (EPI == 1) v = tanh_fast(v);
        else v = fmaxf(v, 0.0f);
        if (EPI == 2) Cf[(size_t)(rbase + q) * N + col] = v;
        else Ch[(size_t)(rbase + q) * N + col] = (f16)v;
      }
    }
  }
}

extern "C" void kernel_launch(void* const* d_in, const int* in_sizes, int n_in,
                              void* d_out, int out_size, void* d_ws, size_t ws_size,
                              hipStream_t stream) {
  const float* x   = (const float*)d_in[0];
  const float* W0  = (const float*)d_in[1];
  const float* b0  = (const float*)d_in[2];
  const float* W1  = (const float*)d_in[3];
  const float* b1  = (const float*)d_in[4];
  const float* cw1 = (const float*)d_in[5];
  const float* KW1 = (const float*)d_in[7];
  const float* Kb1 = (const float*)d_in[8];
  const float* W2  = (const float*)d_in[9];
  const float* b2  = (const float*)d_in[10];
  const float* cw2 = (const float*)d_in[11];
  const float* KW2 = (const float*)d_in[13];
  const float* Kb2 = (const float*)d_in[14];
  const float* W3  = (const float*)d_in[15];
  const float* b3  = (const float*)d_in[16];

  const int B = 4096, IN = 1024, H = 2048, OUT = 1024;

  char* ws = (char*)d_ws;
  size_t off = 0;
  auto alloc = [&](size_t bytes) {
    char* p = ws + off;
    off = (off + bytes + 255) & ~(size_t)255;
    return p;
  };
  f16* xh    = (f16*)alloc((size_t)B * IN * 2);
  f16* W0T   = (f16*)alloc((size_t)H * IN * 2);
  f16* W1T   = (f16*)alloc((size_t)H * H * 2);
  f16* KW1T  = (f16*)alloc((size_t)H * H * 2);
  f16* W2T   = (f16*)alloc((size_t)H * H * 2);
  f16* KW2T  = (f16*)alloc((size_t)H * H * 2);
  f16* W3T   = (f16*)alloc((size_t)OUT * H * 2);
  f16* hA    = (f16*)alloc((size_t)B * H * 2);
  f16* hB    = (f16*)alloc((size_t)B * H * 2);
  float* p1  = (float*)alloc((size_t)H * 4);
  float* p2  = (float*)alloc((size_t)H * 4);
  float* pp  = (float*)alloc((size_t)16 * H * 4);
  (void)ws_size;

  cast_f32_f16<<<(B * IN / 4 + 255) / 256, 256, 0, stream>>>(x, xh, B * IN / 4);

  TD6 td;
  td.d[0] = { W0,  W0T,  IN, H };
  td.d[1] = { W1,  W1T,  H,  H };
  td.d[2] = { KW1, KW1T, H,  H };
  td.d[3] = { W2,  W2T,  H,  H };
  td.d[4] = { KW2, KW2T, H,  H };
  td.d[5] = { W3,  W3T,  H,  OUT };
  cast_transpose6<<<dim3(H / 64, H / 32, 6), 256, 0, stream>>>(td);

  cosmic_pp2<<<(16 * H + 255) / 256, 256, 0, stream>>>(cw1, cw2, pp, H);
  cosmic_fin2<<<(2 * H + 255) / 256, 256, 0, stream>>>(pp, p1, p2, H);

  // G0-G4: r12 kernel, 256x128 tile, grid 16x16=256, 2 blocks/CU.
  {
    int gx = H / 128;
    dim3 g(gx * (B / 256));
    gemm12<0><<<g, 256, 0, stream>>>(xh, W0T, b0,  nullptr, hA, B, H, IN, gx);
    gemm12<0><<<g, 256, 0, stream>>>(hA, W1T, b1,  nullptr, hB, B, H, H,  gx);
    gemm12<1><<<g, 256, 0, stream>>>(hB, KW1T, Kb1, p1,     hA, B, H, H,  gx);
    gemm12<0><<<g, 256, 0, stream>>>(hA, W2T, b2,  nullptr, hB, B, H, H,  gx);
    gemm12<1><<<g, 256, 0, stream>>>(hB, KW2T, Kb2, p2,     hA, B, H, H,  gx);
  }
  // G5: r9 template, 128x64 tile, grid 16x32=512 -> 2-3 blocks/CU.
  {
    int gx = OUT / 64;
    dim3 g(gx * (B / 128));
    gemm_f16<2, 128, 64, 3><<<g, 256, 0, stream>>>(hA, W3T, b3, nullptr, nullptr, (float*)d_out, B, OUT, H, gx);
  }
}

// Round 13
// 210.741 us; speedup vs baseline: 1.2437x; 1.2437x over previous
//
#include <hip/hip_runtime.h>
#include <math.h>

// B=4096, IN=1024, H=2048, OUT=1024
// cosmic layer == broadcast prob[r] = (1/H)*(prod_{d,k} cos(cw[d,r,k]))^2
// Network = 6 fp16-MFMA GEMMs (16x16x32) with fused bias/relu/tanh epilogues.
//
// r13 = r9 (best: 211.9 us) + faster weight transpose.
// GEMM: 128x128 tile (G5: 128x64), BK=64, 256 thr (4 waves 2x2, per-wave
// 64x64), conflict-free 128B-row XOR(r&7) layout, double-buffered LDS
// 64 KB -> 2 blocks/CU (independent barrier domains, m114 TLP), counted
// vmcnt (T4), split lgkm clusters (rule 18), setprio (T5), XCD swizzle (T1).
// Design-space note: BK=32 variants (r5/r8/r12) all regress; 256-wide tiles
// can't fill the machine at N=2048; fp8 numerically excluded.

typedef _Float16 f16;
typedef _Float16 f16x8 __attribute__((ext_vector_type(8)));
typedef _Float16 f16x4 __attribute__((ext_vector_type(4)));
typedef float f32x4 __attribute__((ext_vector_type(4)));

#define GLD16(gp, lp) __builtin_amdgcn_global_load_lds( \
    (const __attribute__((address_space(1))) unsigned int*)(gp), \
    (__attribute__((address_space(3))) unsigned int*)(lp), 16, 0, 0)

__device__ __forceinline__ float tanh_fast(float x) {
  return 1.0f - 2.0f / (__expf(2.0f * x) + 1.0f);
}

// ---------------- fp32 -> fp16 cast ----------------
__global__ void cast_f32_f16(const float* __restrict__ in, f16* __restrict__ out, int n4) {
  int i = blockIdx.x * 256 + threadIdx.x;
  if (i < n4) {
    float4 v = ((const float4*)in)[i];
    f16x4 o = { (f16)v.x, (f16)v.y, (f16)v.z, (f16)v.w };
    ((f16x4*)out)[i] = o;
  }
}

// ------- merged cast+transpose: W (K,N) f32 -> WT (N,K) f16 row-major -------
// 64(K) x 64(N) f32 tiles, 256 thr; pad-65 LDS: read phase 2-way max (free),
// stores 128B contiguous per 8 lanes.
struct TD { const float* src; f16* dst; int K; int N; };
struct TD6 { TD d[6]; };

__global__ void cast_transpose6(TD6 a) {
  TD d = a.d[blockIdx.z];
  const int bx = blockIdx.x * 64;   // N
  const int by = blockIdx.y * 64;   // K
  if (bx >= d.N || by >= d.K) return;
  __shared__ float tile[64 * 65];
  const int t = threadIdx.x;
#pragma unroll
  for (int p = 0; p < 4; ++p) {
    int idx = p * 256 + t;
    int row = idx >> 4;             // 0..63 (K)
    int c4  = (idx & 15) * 4;       // 0..60 (N)
    float4 v = *(const float4*)&d.src[(size_t)(by + row) * d.N + bx + c4];
    *(float4*)&tile[row * 65 + c4] = v;
  }
  __syncthreads();
#pragma unroll
  for (int sp = 0; sp < 2; ++sp) {
    int n  = sp * 32 + (t >> 3);    // 0..63 (N)
    int k8 = (t & 7) * 8;           // 0..56 (K)
    f16x8 o;
#pragma unroll
    for (int j = 0; j < 8; ++j) o[j] = (f16)tile[(k8 + j) * 65 + n];
    *(f16x8*)&d.dst[(size_t)(bx + n) * d.K + by + k8] = o;
  }
}

// ---------------- cosmic prob, 2-pass, both tensors fused ----------------
__global__ void cosmic_pp2(const float* __restrict__ cw1, const float* __restrict__ cw2,
                           float* __restrict__ pp, int H) {
  int i = blockIdx.x * 256 + threadIdx.x;   // 0 .. 16H
  if (i >= 16 * H) return;
  const float* cw = (i < 8 * H) ? cw1 : cw2;
  int j = (i < 8 * H) ? i : i - 8 * H;
  const float* a = cw + (size_t)j * H;
  pp[i] = cosf(a[0]) * cosf(a[1]) * cosf(a[2]);
}
__global__ void cosmic_fin2(const float* __restrict__ pp, float* __restrict__ p1,
                            float* __restrict__ p2, int H) {
  int r = blockIdx.x * 256 + threadIdx.x;   // 0 .. 2H
  if (r >= 2 * H) return;
  int rr = (r < H) ? r : r - H;
  const float* base = pp + ((r < H) ? 0 : 8 * H);
  float p = 1.0f;
#pragma unroll
  for (int d = 0; d < 8; ++d) p *= base[d * H + rr];
  float v = p * p / (float)H;
  if (r < H) p1[rr] = v; else p2[rr] = v;
}

// ---------------- fp16 MFMA GEMM (16x16x32), BK=64, dbuf, 2 blk/CU ----------------
// A: (M,K) f16 row-major. BT: (N,K) f16 row-major.
// EPI 0: relu->f16  1: tanh(+prob)->f16  2: relu->f32
// 256 thr = 4 waves (2M x 2N); per-wave (BM/2) x (BN/2).
template <int EPI, int BM, int BN, int MINW>
__global__ __launch_bounds__(256, MINW)
void gemm_f16(const f16* __restrict__ A, const f16* __restrict__ BT,
              const float* __restrict__ bias, const float* __restrict__ prob,
              f16* __restrict__ Ch, float* __restrict__ Cf,
              int M, int N, int K, int GX) {
  constexpr int ASZ = BM * 64;            // f16 per A buffer (BK=64)
  constexpr int BSZ = BN * 64;            // f16 per B buffer
  constexpr int MR  = BM / 32;            // A frag repeats per wave
  constexpr int NR  = BN / 32;            // B frag repeats per wave
  constexpr int RA  = ASZ / 2048;         // A stage rounds (256 thr * 8 f16)
  constexpr int RB  = BSZ / 2048;         // B stage rounds
  constexpr int NLD = RA + RB;            // glds per tile
  __shared__ f16 lds[2 * (ASZ + BSZ)];    // 64 KB (128x128) / 48 KB (128x64)
  f16* As = lds;
  f16* Bs = lds + 2 * ASZ;

  const int t = threadIdx.x;

  // XCD-aware swizzle (nwg % 8 == 0 for all our grids)
  const int nwg = gridDim.x;
  const int bid = blockIdx.x;
  const int swz = (bid & 7) * (nwg >> 3) + (bid >> 3);
  const int bx = swz % GX;
  const int by = swz / GX;
  const int m0 = by * BM;
  const int n0 = bx * BN;

  // staging: LDS dest linear (wave lanes -> consecutive 16B); XOR swizzle
  // (chunk ^= row&7, 8 chunks per 128B row) pre-applied to GLOBAL source
  // (rule 21). Each row = one permuted-within-128B coalesced segment.
  auto stage_all = [&](int kt, int buf) {
    const int k0 = kt << 6;
#pragma unroll
    for (int q = 0; q < RA; ++q) {
      int F = q * 2048 + t * 8;
      int r = F >> 6, c = (F >> 3) & 7;
      GLD16(A + (size_t)(m0 + r) * K + k0 + ((c ^ (r & 7)) << 3), As + buf * ASZ + F);
    }
#pragma unroll
    for (int q = 0; q < RB; ++q) {
      int F = q * 2048 + t * 8;
      int r = F >> 6, c = (F >> 3) & 7;
      GLD16(BT + (size_t)(n0 + r) * K + k0 + ((c ^ (r & 7)) << 3), Bs + buf * BSZ + F);
    }
  };

  const int wave = t >> 6, lane = t & 63;
  const int wr = wave >> 1, wc = wave & 1;   // 2M x 2N
  const int l16 = lane & 15, kq = lane >> 4;

  f32x4 acc[MR][NR] = {};

  const int nt = K >> 6;
  stage_all(0, 0);
  stage_all(1, 1);
  int cur = 0;
  for (int kt = 0; kt < nt; ++kt) {
    // tile kt's loads retired; tile kt+1's NLD stay in flight
    if (kt + 1 < nt) asm volatile("s_waitcnt vmcnt(%0)" :: "i"(NLD) : "memory");
    else             asm volatile("s_waitcnt vmcnt(0)" ::: "memory");
    __builtin_amdgcn_s_barrier();

    const f16* Ab = As + cur * ASZ;
    const f16* Bb = Bs + cur * BSZ;
    f16x8 a[2][MR], b[2][NR];
#pragma unroll
    for (int s = 0; s < 2; ++s) {
      const int cc = s * 4 + kq;          // 16B chunk (8 per 128B row)
#pragma unroll
      for (int mr = 0; mr < MR; ++mr) {
        int row = wr * (MR * 16) + mr * 16 + l16;
        a[s][mr] = *(const f16x8*)&Ab[row * 64 + ((cc ^ (row & 7)) << 3)];
      }
#pragma unroll
      for (int nr = 0; nr < NR; ++nr) {
        int row = wc * (NR * 16) + nr * 16 + l16;
        b[s][nr] = *(const f16x8*)&Bb[row * 64 + ((cc ^ (row & 7)) << 3)];
      }
      __builtin_amdgcn_sched_barrier(0);  // pin: s0 reads issue before s1
    }
    // cluster 0: wait s0's reads (s1's stay outstanding under MFMA)
    asm volatile("s_waitcnt lgkmcnt(%0)" :: "i"(MR + NR) : "memory");
    __builtin_amdgcn_sched_barrier(0);
    __builtin_amdgcn_s_setprio(1);
#pragma unroll
    for (int mr = 0; mr < MR; ++mr)
#pragma unroll
      for (int nr = 0; nr < NR; ++nr)
        acc[mr][nr] = __builtin_amdgcn_mfma_f32_16x16x32_f16(a[0][mr], b[0][nr], acc[mr][nr], 0, 0, 0);
    __builtin_amdgcn_s_setprio(0);
    // all reads of buf cur complete in every wave -> safe to overwrite after bar
    asm volatile("s_waitcnt lgkmcnt(0)" ::: "memory");
    __builtin_amdgcn_sched_barrier(0);
    __builtin_amdgcn_s_barrier();
    if (kt + 2 < nt) stage_all(kt + 2, cur);   // into just-freed buffer
    __builtin_amdgcn_s_setprio(1);
#pragma unroll
    for (int mr = 0; mr < MR; ++mr)
#pragma unroll
      for (int nr = 0; nr < NR; ++nr)
        acc[mr][nr] = __builtin_amdgcn_mfma_f32_16x16x32_f16(a[1][mr], b[1][nr], acc[mr][nr], 0, 0, 0);
    __builtin_amdgcn_s_setprio(0);
    cur ^= 1;
  }

  // epilogue: 16x16 C/D layout col=lane&15, row=(lane>>4)*4+q
#pragma unroll
  for (int nr = 0; nr < NR; ++nr) {
    const int col = n0 + wc * (NR * 16) + nr * 16 + l16;
    float bn = bias[col];
    if (EPI == 1) bn += prob[col];
#pragma unroll
    for (int mr = 0; mr < MR; ++mr) {
      const int rbase = m0 + wr * (MR * 16) + mr * 16 + kq * 4;
#pragma unroll
      for (int q = 0; q < 4; ++q) {
        float v = acc[mr][nr][q] + bn;
        if (EPI == 1) v = tanh_fast(v);
        else v = fmaxf(v, 0.0f);
        if (EPI == 2) Cf[(size_t)(rbase + q) * N + col] = v;
        else Ch[(size_t)(rbase + q) * N + col] = (f16)v;
      }
    }
  }
}

extern "C" void kernel_launch(void* const* d_in, const int* in_sizes, int n_in,
                              void* d_out, int out_size, void* d_ws, size_t ws_size,
                              hipStream_t stream) {
  const float* x   = (const float*)d_in[0];
  const float* W0  = (const float*)d_in[1];
  const float* b0  = (const float*)d_in[2];
  const float* W1  = (const float*)d_in[3];
  const float* b1  = (const float*)d_in[4];
  const float* cw1 = (const float*)d_in[5];
  const float* KW1 = (const float*)d_in[7];
  const float* Kb1 = (const float*)d_in[8];
  const float* W2  = (const float*)d_in[9];
  const float* b2  = (const float*)d_in[10];
  const float* cw2 = (const float*)d_in[11];
  const float* KW2 = (const float*)d_in[13];
  const float* Kb2 = (const float*)d_in[14];
  const float* W3  = (const float*)d_in[15];
  const float* b3  = (const float*)d_in[16];

  const int B = 4096, IN = 1024, H = 2048, OUT = 1024;

  char* ws = (char*)d_ws;
  size_t off = 0;
  auto alloc = [&](size_t bytes) {
    char* p = ws + off;
    off = (off + bytes + 255) & ~(size_t)255;
    return p;
  };
  f16* xh    = (f16*)alloc((size_t)B * IN * 2);
  f16* W0T   = (f16*)alloc((size_t)H * IN * 2);
  f16* W1T   = (f16*)alloc((size_t)H * H * 2);
  f16* KW1T  = (f16*)alloc((size_t)H * H * 2);
  f16* W2T   = (f16*)alloc((size_t)H * H * 2);
  f16* KW2T  = (f16*)alloc((size_t)H * H * 2);
  f16* W3T   = (f16*)alloc((size_t)OUT * H * 2);
  f16* hA    = (f16*)alloc((size_t)B * H * 2);
  f16* hB    = (f16*)alloc((size_t)B * H * 2);
  float* p1  = (float*)alloc((size_t)H * 4);
  float* p2  = (float*)alloc((size_t)H * 4);
  float* pp  = (float*)alloc((size_t)16 * H * 4);
  (void)ws_size;

  cast_f32_f16<<<(B * IN / 4 + 255) / 256, 256, 0, stream>>>(x, xh, B * IN / 4);

  TD6 td;
  td.d[0] = { W0,  W0T,  IN, H };
  td.d[1] = { W1,  W1T,  H,  H };
  td.d[2] = { KW1, KW1T, H,  H };
  td.d[3] = { W2,  W2T,  H,  H };
  td.d[4] = { KW2, KW2T, H,  H };
  td.d[5] = { W3,  W3T,  H,  OUT };
  cast_transpose6<<<dim3(H / 64, H / 64, 6), 256, 0, stream>>>(td);

  cosmic_pp2<<<(16 * H + 255) / 256, 256, 0, stream>>>(cw1, cw2, pp, H);
  cosmic_fin2<<<(2 * H + 255) / 256, 256, 0, stream>>>(pp, p1, p2, H);

  // G0-G4: 128x128 tile, 64 KB LDS, grid 16x32=512 -> 2 blocks/CU.
  {
    int gx = H / 128, gy = B / 128;
    dim3 g(gx * gy);
    gemm_f16<0, 128, 128, 2><<<g, 256, 0, stream>>>(xh, W0T, b0,  nullptr, hA, nullptr, B, H, IN, gx);
    gemm_f16<0, 128, 128, 2><<<g, 256, 0, stream>>>(hA, W1T, b1,  nullptr, hB, nullptr, B, H, H,  gx);
    gemm_f16<1, 128, 128, 2><<<g, 256, 0, stream>>>(hB, KW1T, Kb1, p1,     hA, nullptr, B, H, H,  gx);
    gemm_f16<0, 128, 128, 2><<<g, 256, 0, stream>>>(hA, W2T, b2,  nullptr, hB, nullptr, B, H, H,  gx);
    gemm_f16<1, 128, 128, 2><<<g, 256, 0, stream>>>(hB, KW2T, Kb2, p2,     hA, nullptr, B, H, H,  gx);
  }
  // G5: 128x64 tile, 48 KB LDS, grid 16x32=512 -> up to 3 blocks/CU.
  {
    int gx = OUT / 64, gy = B / 128;
    dim3 g(gx * gy);
    gemm_f16<2, 128, 64, 3><<<g, 256, 0, stream>>>(hA, W3T, b3, nullptr, nullptr, (float*)d_out, B, OUT, H, gx);
  }
}

// Round 15
// 208.878 us; speedup vs baseline: 1.2547x; 1.0089x over previous
//
#include <hip/hip_runtime.h>
#include <math.h>

// B=4096, IN=1024, H=2048, OUT=1024
// cosmic layer == broadcast prob[r] = (1/H)*(prod_{d,k} cos(cw[d,r,k]))^2
// Network = 6 fp16-MFMA GEMMs (16x16x32) with fused bias/relu/tanh epilogues.
//
// r15 = r14 with the cast-slice coverage bug fixed (4 passes x 1024 f32 per
// block; r14 covered only 1/4 of x -> poison in xh).
// GEMM: 128x128 tile (G5: 128x64), BK=64, 256 thr (4 waves 2x2, per-wave
// 64x64), conflict-free 128B-row XOR(r&7) layout, double-buffered LDS
// 64 KB -> 2 blocks/CU (independent barrier domains, m114 TLP), counted
// vmcnt (T4), split lgkm clusters (rule 18), setprio (T5), XCD swizzle (T1).

typedef _Float16 f16;
typedef _Float16 f16x8 __attribute__((ext_vector_type(8)));
typedef _Float16 f16x4 __attribute__((ext_vector_type(4)));
typedef float f32x4 __attribute__((ext_vector_type(4)));

#define GLD16(gp, lp) __builtin_amdgcn_global_load_lds( \
    (const __attribute__((address_space(1))) unsigned int*)(gp), \
    (__attribute__((address_space(3))) unsigned int*)(lp), 16, 0, 0)

__device__ __forceinline__ float tanh_fast(float x) {
  return 1.0f - 2.0f / (__expf(2.0f * x) + 1.0f);
}

// ------- merged prep: 6x cast+transpose + 1x plain cast (z slice 6) -------
// Transpose slices: 64(K) x 64(N) f32 tiles, 256 thr; pad-65 LDS.
// Cast slice: x (4096x1024 f32) -> f16 row-major; 4096 f32 per block
// (4 passes x 256 thr x float4), 1024 blocks cover B*IN exactly.
struct TD { const float* src; f16* dst; int K; int N; };
struct TD7 { TD d[6]; const float* xsrc; f16* xdst; };

__global__ void prep7(TD7 a) {
  const int t = threadIdx.x;
  if (blockIdx.z == 6) {
    const size_t bid = (size_t)blockIdx.y * 32 + blockIdx.x;   // 0..1023
#pragma unroll
    for (int p = 0; p < 4; ++p) {
      size_t base = bid * 4096 + (size_t)p * 1024 + (size_t)t * 4;
      float4 v = *(const float4*)&a.xsrc[base];
      f16x4 o = { (f16)v.x, (f16)v.y, (f16)v.z, (f16)v.w };
      *(f16x4*)&a.xdst[base] = o;
    }
    return;
  }
  TD d = a.d[blockIdx.z];
  const int bx = blockIdx.x * 64;   // N
  const int by = blockIdx.y * 64;   // K
  if (bx >= d.N || by >= d.K) return;
  __shared__ float tile[64 * 65];
#pragma unroll
  for (int p = 0; p < 4; ++p) {
    int idx = p * 256 + t;
    int row = idx >> 4;             // 0..63 (K)
    int c4  = (idx & 15) * 4;       // 0..60 (N)
    float4 v = *(const float4*)&d.src[(size_t)(by + row) * d.N + bx + c4];
    *(float4*)&tile[row * 65 + c4] = v;
  }
  __syncthreads();
#pragma unroll
  for (int sp = 0; sp < 2; ++sp) {
    int n  = sp * 32 + (t >> 3);    // 0..63 (N)
    int k8 = (t & 7) * 8;           // 0..56 (K)
    f16x8 o;
#pragma unroll
    for (int j = 0; j < 8; ++j) o[j] = (f16)tile[(k8 + j) * 65 + n];
    *(f16x8*)&d.dst[(size_t)(bx + n) * d.K + by + k8] = o;
  }
}

// ---------------- cosmic prob, 2-pass, both tensors fused ----------------
__global__ void cosmic_pp2(const float* __restrict__ cw1, const float* __restrict__ cw2,
                           float* __restrict__ pp, int H) {
  int i = blockIdx.x * 256 + threadIdx.x;   // 0 .. 16H
  if (i >= 16 * H) return;
  const float* cw = (i < 8 * H) ? cw1 : cw2;
  int j = (i < 8 * H) ? i : i - 8 * H;
  const float* a = cw + (size_t)j * H;
  pp[i] = cosf(a[0]) * cosf(a[1]) * cosf(a[2]);
}
__global__ void cosmic_fin2(const float* __restrict__ pp, float* __restrict__ p1,
                            float* __restrict__ p2, int H) {
  int r = blockIdx.x * 256 + threadIdx.x;   // 0 .. 2H
  if (r >= 2 * H) return;
  int rr = (r < H) ? r : r - H;
  const float* base = pp + ((r < H) ? 0 : 8 * H);
  float p = 1.0f;
#pragma unroll
  for (int d = 0; d < 8; ++d) p *= base[d * H + rr];
  float v = p * p / (float)H;
  if (r < H) p1[rr] = v; else p2[rr] = v;
}

// ---------------- fp16 MFMA GEMM (16x16x32), BK=64, dbuf, 2 blk/CU ----------------
// A: (M,K) f16 row-major. BT: (N,K) f16 row-major.
// EPI 0: relu->f16  1: tanh(+prob)->f16  2: relu->f32
// 256 thr = 4 waves (2M x 2N); per-wave (BM/2) x (BN/2).
template <int EPI, int BM, int BN, int MINW>
__global__ __launch_bounds__(256, MINW)
void gemm_f16(const f16* __restrict__ A, const f16* __restrict__ BT,
              const float* __restrict__ bias, const float* __restrict__ prob,
              f16* __restrict__ Ch, float* __restrict__ Cf,
              int M, int N, int K, int GX) {
  constexpr int ASZ = BM * 64;            // f16 per A buffer (BK=64)
  constexpr int BSZ = BN * 64;            // f16 per B buffer
  constexpr int MR  = BM / 32;            // A frag repeats per wave
  constexpr int NR  = BN / 32;            // B frag repeats per wave
  constexpr int RA  = ASZ / 2048;         // A stage rounds (256 thr * 8 f16)
  constexpr int RB  = BSZ / 2048;         // B stage rounds
  constexpr int NLD = RA + RB;            // glds per tile
  __shared__ f16 lds[2 * (ASZ + BSZ)];    // 64 KB (128x128) / 48 KB (128x64)
  f16* As = lds;
  f16* Bs = lds + 2 * ASZ;

  const int t = threadIdx.x;

  // XCD-aware swizzle (nwg % 8 == 0 for all our grids)
  const int nwg = gridDim.x;
  const int bid = blockIdx.x;
  const int swz = (bid & 7) * (nwg >> 3) + (bid >> 3);
  const int bx = swz % GX;
  const int by = swz / GX;
  const int m0 = by * BM;
  const int n0 = bx * BN;

  // staging: LDS dest linear (wave lanes -> consecutive 16B); XOR swizzle
  // (chunk ^= row&7, 8 chunks per 128B row) pre-applied to GLOBAL source
  // (rule 21). Each row = one permuted-within-128B coalesced segment.
  auto stage_all = [&](int kt, int buf) {
    const int k0 = kt << 6;
#pragma unroll
    for (int q = 0; q < RA; ++q) {
      int F = q * 2048 + t * 8;
      int r = F >> 6, c = (F >> 3) & 7;
      GLD16(A + (size_t)(m0 + r) * K + k0 + ((c ^ (r & 7)) << 3), As + buf * ASZ + F);
    }
#pragma unroll
    for (int q = 0; q < RB; ++q) {
      int F = q * 2048 + t * 8;
      int r = F >> 6, c = (F >> 3) & 7;
      GLD16(BT + (size_t)(n0 + r) * K + k0 + ((c ^ (r & 7)) << 3), Bs + buf * BSZ + F);
    }
  };

  const int wave = t >> 6, lane = t & 63;
  const int wr = wave >> 1, wc = wave & 1;   // 2M x 2N
  const int l16 = lane & 15, kq = lane >> 4;

  f32x4 acc[MR][NR] = {};

  const int nt = K >> 6;
  stage_all(0, 0);
  stage_all(1, 1);
  int cur = 0;
  for (int kt = 0; kt < nt; ++kt) {
    // tile kt's loads retired; tile kt+1's NLD stay in flight
    if (kt + 1 < nt) asm volatile("s_waitcnt vmcnt(%0)" :: "i"(NLD) : "memory");
    else             asm volatile("s_waitcnt vmcnt(0)" ::: "memory");
    __builtin_amdgcn_s_barrier();

    const f16* Ab = As + cur * ASZ;
    const f16* Bb = Bs + cur * BSZ;
    f16x8 a[2][MR], b[2][NR];
#pragma unroll
    for (int s = 0; s < 2; ++s) {
      const int cc = s * 4 + kq;          // 16B chunk (8 per 128B row)
#pragma unroll
      for (int mr = 0; mr < MR; ++mr) {
        int row = wr * (MR * 16) + mr * 16 + l16;
        a[s][mr] = *(const f16x8*)&Ab[row * 64 + ((cc ^ (row & 7)) << 3)];
      }
#pragma unroll
      for (int nr = 0; nr < NR; ++nr) {
        int row = wc * (NR * 16) + nr * 16 + l16;
        b[s][nr] = *(const f16x8*)&Bb[row * 64 + ((cc ^ (row & 7)) << 3)];
      }
      __builtin_amdgcn_sched_barrier(0);  // pin: s0 reads issue before s1
    }
    // cluster 0: wait s0's reads (s1's stay outstanding under MFMA)
    asm volatile("s_waitcnt lgkmcnt(%0)" :: "i"(MR + NR) : "memory");
    __builtin_amdgcn_sched_barrier(0);
    __builtin_amdgcn_s_setprio(1);
#pragma unroll
    for (int mr = 0; mr < MR; ++mr)
#pragma unroll
      for (int nr = 0; nr < NR; ++nr)
        acc[mr][nr] = __builtin_amdgcn_mfma_f32_16x16x32_f16(a[0][mr], b[0][nr], acc[mr][nr], 0, 0, 0);
    __builtin_amdgcn_s_setprio(0);
    // all reads of buf cur complete in every wave -> safe to overwrite after bar
    asm volatile("s_waitcnt lgkmcnt(0)" ::: "memory");
    __builtin_amdgcn_sched_barrier(0);
    __builtin_amdgcn_s_barrier();
    if (kt + 2 < nt) stage_all(kt + 2, cur);   // into just-freed buffer
    __builtin_amdgcn_s_setprio(1);
#pragma unroll
    for (int mr = 0; mr < MR; ++mr)
#pragma unroll
      for (int nr = 0; nr < NR; ++nr)
        acc[mr][nr] = __builtin_amdgcn_mfma_f32_16x16x32_f16(a[1][mr], b[1][nr], acc[mr][nr], 0, 0, 0);
    __builtin_amdgcn_s_setprio(0);
    cur ^= 1;
  }

  // epilogue: 16x16 C/D layout col=lane&15, row=(lane>>4)*4+q
#pragma unroll
  for (int nr = 0; nr < NR; ++nr) {
    const int col = n0 + wc * (NR * 16) + nr * 16 + l16;
    float bn = bias[col];
    if (EPI == 1) bn += prob[col];
#pragma unroll
    for (int mr = 0; mr < MR; ++mr) {
      const int rbase = m0 + wr * (MR * 16) + mr * 16 + kq * 4;
#pragma unroll
      for (int q = 0; q < 4; ++q) {
        float v = acc[mr][nr][q] + bn;
        if (EPI == 1) v = tanh_fast(v);
        else v = fmaxf(v, 0.0f);
        if (EPI == 2) Cf[(size_t)(rbase + q) * N + col] = v;
        else Ch[(size_t)(rbase + q) * N + col] = (f16)v;
      }
    }
  }
}

extern "C" void kernel_launch(void* const* d_in, const int* in_sizes, int n_in,
                              void* d_out, int out_size, void* d_ws, size_t ws_size,
                              hipStream_t stream) {
  const float* x   = (const float*)d_in[0];
  const float* W0  = (const float*)d_in[1];
  const float* b0  = (const float*)d_in[2];
  const float* W1  = (const float*)d_in[3];
  const float* b1  = (const float*)d_in[4];
  const float* cw1 = (const float*)d_in[5];
  const float* KW1 = (const float*)d_in[7];
  const float* Kb1 = (const float*)d_in[8];
  const float* W2  = (const float*)d_in[9];
  const float* b2  = (const float*)d_in[10];
  const float* cw2 = (const float*)d_in[11];
  const float* KW2 = (const float*)d_in[13];
  const float* Kb2 = (const float*)d_in[14];
  const float* W3  = (const float*)d_in[15];
  const float* b3  = (const float*)d_in[16];

  const int B = 4096, IN = 1024, H = 2048, OUT = 1024;

  char* ws = (char*)d_ws;
  size_t off = 0;
  auto alloc = [&](size_t bytes) {
    char* p = ws + off;
    off = (off + bytes + 255) & ~(size_t)255;
    return p;
  };
  f16* xh    = (f16*)alloc((size_t)B * IN * 2);
  f16* W0T   = (f16*)alloc((size_t)H * IN * 2);
  f16* W1T   = (f16*)alloc((size_t)H * H * 2);
  f16* KW1T  = (f16*)alloc((size_t)H * H * 2);
  f16* W2T   = (f16*)alloc((size_t)H * H * 2);
  f16* KW2T  = (f16*)alloc((size_t)H * H * 2);
  f16* W3T   = (f16*)alloc((size_t)OUT * H * 2);
  f16* hA    = (f16*)alloc((size_t)B * H * 2);
  f16* hB    = (f16*)alloc((size_t)B * H * 2);
  float* p1  = (float*)alloc((size_t)H * 4);
  float* p2  = (float*)alloc((size_t)H * 4);
  float* pp  = (float*)alloc((size_t)16 * H * 4);
  (void)ws_size;

  TD7 td;
  td.d[0] = { W0,  W0T,  IN, H };
  td.d[1] = { W1,  W1T,  H,  H };
  td.d[2] = { KW1, KW1T, H,  H };
  td.d[3] = { W2,  W2T,  H,  H };
  td.d[4] = { KW2, KW2T, H,  H };
  td.d[5] = { W3,  W3T,  H,  OUT };
  td.xsrc = x;
  td.xdst = xh;
  prep7<<<dim3(H / 64, H / 64, 7), 256, 0, stream>>>(td);

  cosmic_pp2<<<(16 * H + 255) / 256, 256, 0, stream>>>(cw1, cw2, pp, H);
  cosmic_fin2<<<(2 * H + 255) / 256, 256, 0, stream>>>(pp, p1, p2, H);

  // G0-G4: 128x128 tile, 64 KB LDS, grid 16x32=512 -> 2 blocks/CU.
  {
    int gx = H / 128, gy = B / 128;
    dim3 g(gx * gy);
    gemm_f16<0, 128, 128, 2><<<g, 256, 0, stream>>>(xh, W0T, b0,  nullptr, hA, nullptr, B, H, IN, gx);
    gemm_f16<0, 128, 128, 2><<<g, 256, 0, stream>>>(hA, W1T, b1,  nullptr, hB, nullptr, B, H, H,  gx);
    gemm_f16<1, 128, 128, 2><<<g, 256, 0, stream>>>(hB, KW1T, Kb1, p1,     hA, nullptr, B, H, H,  gx);
    gemm_f16<0, 128, 128, 2><<<g, 256, 0, stream>>>(hA, W2T, b2,  nullptr, hB, nullptr, B, H, H,  gx);
    gemm_f16<1, 128, 128, 2><<<g, 256, 0, stream>>>(hB, KW2T, Kb2, p2,     hA, nullptr, B, H, H,  gx);
  }
  // G5: 128x64 tile, 48 KB LDS, grid 16x32=512 -> up to 3 blocks/CU.
  {
    int gx = OUT / 64, gy = B / 128;
    dim3 g(gx * gy);
    gemm_f16<2, 128, 64, 3><<<g, 256, 0, stream>>>(hA, W3T, b3, nullptr, nullptr, (float*)d_out, B, OUT, H, gx);
  }
}